// Round 12
// baseline (1838.508 us; speedup 1.0000x reference)
//
#include <hip/hip_runtime.h>
#include <math.h>

#define NB 64
#define NV 128
#define NEDGE_PER 8128
#define N_EDGE (NB * NEDGE_PER)   // 520192
#define N_EX (NB * NV)            // 8192
#define BID_ROUNDS 64
#define ARR_CAP 128
#define EPS 0.02f

// workspace layout (doubles):
// ws[0..63]    per-sample SmoothL1 sums
// ws[64]       existence BCE sum
// ws[128..383] edge BCE partials (256 blocks)

typedef unsigned long long u64;
typedef unsigned int uint2v __attribute__((ext_vector_type(2)));

__device__ __forceinline__ float sl1f(float d) {
    d = fabsf(d);
    return d < 1.0f ? 0.5f * d * d : d - 0.5f;
}
__device__ __forceinline__ unsigned umin2(unsigned a, unsigned b) { return a < b ? a : b; }

// ---- cross-lane helpers ---------------------------------------------------

template <int CTRL>
__device__ __forceinline__ int dpp_i(int x) {
    return __builtin_amdgcn_update_dpp(0, x, CTRL, 0xF, 0xF, true);
}

// Monotone u32 key of f32; low 8 bits = column idx (1..128). Exact ties break
// to lowest idx; exact f32 minv is re-read from the winning lane so duals stay
// accurate. Sub-quantum mis-picks only swap near-optimal alternates.
__device__ __forceinline__ unsigned f2key(float x, int idx) {
    unsigned b = __float_as_uint(x);
    unsigned m = (unsigned)(((int)b) >> 31) | 0x80000000u;
    return ((b ^ m) & ~0xFFu) | (unsigned)idx;
}
// ARR key: bit 8 = assigned-flag (prefer unassigned among ties).
__device__ __forceinline__ unsigned f2key_arr(float x, bool assigned, int idx) {
    unsigned b = __float_as_uint(x);
    unsigned m = (unsigned)(((int)b) >> 31) | 0x80000000u;
    return ((b ^ m) & ~0x1FFu) | (assigned ? 0x100u : 0u) | (unsigned)idx;
}
// bid key: monotone map of bid > 0, low 8 bits = row idx; max-reduce.
__device__ __forceinline__ unsigned bidkey(float b, int row) {
    return ((__float_as_uint(b) | 0x80000000u) & ~0xFFu) | (unsigned)row;
}

// 64-lane min over 32-bit packed keys, broadcast to all lanes.
__device__ __forceinline__ unsigned wave_minkey32(unsigned k) {
    { unsigned o = (unsigned)dpp_i<0xB1>((int)k);  k = umin2(k, o); }
    { unsigned o = (unsigned)dpp_i<0x4E>((int)k);  k = umin2(k, o); }
    { unsigned o = (unsigned)dpp_i<0x141>((int)k); k = umin2(k, o); }
    { unsigned o = (unsigned)dpp_i<0x140>((int)k); k = umin2(k, o); }
#if __has_builtin(__builtin_amdgcn_permlane16_swap)
    { uint2v r = __builtin_amdgcn_permlane16_swap(k, k, false, false);
      k = umin2(k, umin2(r.x, r.y)); }
#else
    { k = umin2(k, (unsigned)__shfl_xor((int)k, 16)); }
#endif
#if __has_builtin(__builtin_amdgcn_permlane32_swap)
    { uint2v r = __builtin_amdgcn_permlane32_swap(k, k, false, false);
      k = umin2(k, umin2(r.x, r.y)); }
#else
    { k = umin2(k, (unsigned)__shfl_xor((int)k, 32)); }
#endif
    return k;
}

// two-smallest merge; requires k1<=k2 and o1<=o2 (self-pair merge harmless).
__device__ __forceinline__ void min2m(unsigned& k1, unsigned& k2, unsigned o1, unsigned o2) {
    if (k1 <= o1) {
        k2 = umin2(k2, o1);
    } else {
        k2 = umin2(o2, k1);
        k1 = o1;
    }
}
// 64-lane (min, 2nd-min) over per-lane sorted pairs; broadcast.
__device__ __forceinline__ void wave_min2_32(unsigned& k1, unsigned& k2) {
    { unsigned o1 = (unsigned)dpp_i<0xB1>((int)k1),  o2 = (unsigned)dpp_i<0xB1>((int)k2);  min2m(k1, k2, o1, o2); }
    { unsigned o1 = (unsigned)dpp_i<0x4E>((int)k1),  o2 = (unsigned)dpp_i<0x4E>((int)k2);  min2m(k1, k2, o1, o2); }
    { unsigned o1 = (unsigned)dpp_i<0x141>((int)k1), o2 = (unsigned)dpp_i<0x141>((int)k2); min2m(k1, k2, o1, o2); }
    { unsigned o1 = (unsigned)dpp_i<0x140>((int)k1), o2 = (unsigned)dpp_i<0x140>((int)k2); min2m(k1, k2, o1, o2); }
#if __has_builtin(__builtin_amdgcn_permlane16_swap)
    { uint2v r1 = __builtin_amdgcn_permlane16_swap(k1, k1, false, false);
      uint2v r2 = __builtin_amdgcn_permlane16_swap(k2, k2, false, false);
      min2m(k1, k2, r1.x, r2.x); min2m(k1, k2, r1.y, r2.y); }
#else
    { unsigned o1 = (unsigned)__shfl_xor((int)k1, 16), o2 = (unsigned)__shfl_xor((int)k2, 16); min2m(k1, k2, o1, o2); }
#endif
#if __has_builtin(__builtin_amdgcn_permlane32_swap)
    { uint2v r1 = __builtin_amdgcn_permlane32_swap(k1, k1, false, false);
      uint2v r2 = __builtin_amdgcn_permlane32_swap(k2, k2, false, false);
      min2m(k1, k2, r1.x, r2.x); min2m(k1, k2, r1.y, r2.y); }
#else
    { unsigned o1 = (unsigned)__shfl_xor((int)k1, 32), o2 = (unsigned)__shfl_xor((int)k2, 32); min2m(k1, k2, o1, o2); }
#endif
}

__device__ __forceinline__ int rl_i(int v, int sl) {
    return __builtin_amdgcn_readlane(v, sl);
}
__device__ __forceinline__ float rl_f(float v, int sl) {
    return __int_as_float(__builtin_amdgcn_readlane(__float_as_int(v), sl));
}

// ---- Hungarian: swizzled cost planes + colred + eps(0.02)-auction + ARR
//      + single-source shift-trick SAP. One wave per sample. ----------------

// cost plane layout: entry (0-based row r, 0-based col-half c0) stored at
// r*64 + (c0 ^ (r&31)) -> 2-way banks for both row-broadcast and row-scan.

__global__ __launch_bounds__(64, 1) void hungarian_kernel(
    const float* __restrict__ pv,     // [B,V,3]
    const float* __restrict__ pe,     // [B,V]
    const float* __restrict__ tv,     // [B,V,3]
    const int*   __restrict__ counts, // [B]
    double* __restrict__ ws_sl1)      // [B]
{
    const int b = blockIdx.x;
    const int lane = threadIdx.x;
    const int c = counts[b];

    __shared__ float  s_costA[NV * 64];  // cols 1..64   (32 KB, swizzled)
    __shared__ float  s_costB[NV * 64];  // cols 65..128 (32 KB, swizzled)
    __shared__ float4 s_row[NV];
    __shared__ float  s_pe[NV];
    __shared__ float  s_v[NV];           // column potentials (LDS master copy)
    __shared__ float  s_u[NV];           // row potentials
    __shared__ int    s_x[NV];           // row -> col (0 = free)
    __shared__ float  s_rm1[NV], s_rm2[NV];
    __shared__ unsigned s_bid[NV];

    const float* pvb = pv + (size_t)b * NV * 3;
    const float* peb = pe + (size_t)b * NV;
    const float* tvb = tv + (size_t)b * NV * 3;

    // lane owns rows/cols (1-based): rA=jA=lane+1, rB=jB=lane+65
    {
        float x0 = pvb[lane * 3 + 0], y0 = pvb[lane * 3 + 1], z0 = pvb[lane * 3 + 2];
        float x1 = pvb[(lane + 64) * 3 + 0], y1 = pvb[(lane + 64) * 3 + 1], z1 = pvb[(lane + 64) * 3 + 2];
        float e0 = peb[lane], e1 = peb[lane + 64];
        s_row[lane]      = make_float4(x0, y0, z0, fabsf(e0 - 1.0f));
        s_row[lane + 64] = make_float4(x1, y1, z1, fabsf(e1 - 1.0f));
        s_pe[lane]       = e0;
        s_pe[lane + 64]  = e1;
    }
    const float tAx = tvb[lane * 3 + 0], tAy = tvb[lane * 3 + 1], tAz = tvb[lane * 3 + 2];
    const float tBx = tvb[(lane + 64) * 3 + 0], tBy = tvb[(lane + 64) * 3 + 1], tBz = tvb[(lane + 64) * 3 + 2];

    const int jA = lane + 1, jB = lane + 65;
    const int rA = lane + 1, rB = lane + 65;
    const bool realA = (jA <= c), realB = (jB <= c);

    __syncthreads();

    // ---- Phase 0: build swizzled cost planes (f32-exact, reference order) --
    #pragma unroll 4
    for (int r = 0; r < NV; ++r) {
        float4 row = s_row[r];
        float per = s_pe[r];
        float cAv = realA ? (((fabsf(row.x - tAx) + fabsf(row.y - tAy)) + fabsf(row.z - tAz)) + row.w) : per;
        float cBv = realB ? (((fabsf(row.x - tBx) + fabsf(row.y - tBy)) + fabsf(row.z - tBz)) + row.w) : per;
        const int a = r * 64 + (lane ^ (r & 31));
        s_costA[a] = cAv;
        s_costB[a] = cBv;
    }
    __syncthreads();

    // ---- Phase A: column reduction (v[j] = min_i C[i][j]) -----------------
    float bestA = 3.4e38f, bestB = 3.4e38f;
    #pragma unroll 4
    for (int r = 0; r < NV; ++r) {
        const int a = r * 64 + (lane ^ (r & 31));
        bestA = fminf(bestA, s_costA[a]);
        bestB = fminf(bestB, s_costB[a]);
    }
    float vA = bestA, vB = bestB;   // this lane's column potentials
    float uA = 0.0f, uB = 0.0f;
    int pA = 0, pB = 0;             // col -> row (0 = free)
    s_v[jA - 1] = vA; s_v[jB - 1] = vB;
    s_x[rA - 1] = 0;  s_x[rB - 1] = 0;
    s_u[rA - 1] = 0.0f; s_u[rB - 1] = 0.0f;

    // ---- Phase B: eps(0.02)-scaled Jacobi auction rounds ------------------
    // Bid accept drops v by (m2-m1)+EPS: price wars make >= EPS progress per
    // accept and resolve in ~spread/EPS rounds. Assigned edge stays exactly
    // tight (u[w] = m2+EPS); other reduced costs >= -EPS. Final matching
    // within ~n*EPS of optimal (typ. few differing pairs; loss budget 4.2e-2).
    // Stall patience 16: nfree legitimately plateaus while prices drop.
    int prevFree = NV + 1, stall = 0;
    for (int round = 0; round < BID_ROUNDS; ++round) {
        const int xAcur = s_x[rA - 1];
        const int xBcur = s_x[rB - 1];
        const u64 fA = __ballot(xAcur == 0);
        const u64 fB = __ballot(xBcur == 0);
        const int nfree = __popcll(fA) + __popcll(fB);
        if (nfree == 0 || nfree <= 8) break;
        if (nfree >= prevFree) { if (++stall >= 16) break; } else stall = 0;
        prevFree = nfree;

        s_bid[jA - 1] = 0u;
        s_bid[jB - 1] = 0u;

        // scan my free rows (exact f32 min/second-min, rotated tie-break)
        #pragma unroll
        for (int half = 0; half < 2; ++half) {
            const int ri = (half == 0) ? rA : rB;            // 1-based row
            const int xcur = (half == 0) ? xAcur : xBcur;
            if (xcur != 0) continue;
            const int r0 = ri - 1;
            const int swz = r0 & 31;
            float m1 = 3.4e38f, m2 = 3.4e38f;
            int j1 = 0, rot1 = 1000;
            #pragma unroll 4
            for (int j0 = 0; j0 < 64; ++j0) {
                const int a = r0 * 64 + (j0 ^ swz);
                float ca = s_costA[a] - s_v[j0];
                float cb = s_costB[a] - s_v[j0 + 64];
                int rotA = (j0 + 1 - ri) & 127;
                int rotB = (j0 + 65 - ri) & 127;
                if (ca < m1 || (ca == m1 && rotA < rot1)) { m2 = m1; m1 = ca; j1 = j0 + 1; rot1 = rotA; }
                else if (ca < m2) m2 = ca;
                if (cb < m1 || (cb == m1 && rotB < rot1)) { m2 = m1; m1 = cb; j1 = j0 + 65; rot1 = rotB; }
                else if (cb < m2) m2 = cb;
            }
            s_rm1[r0] = m1;
            s_rm2[r0] = m2;
            atomicMax(&s_bid[j1 - 1], bidkey((m2 - m1) + EPS, ri));
        }

        // column accept (this lane's two columns) — eps-augmented
        {
            unsigned bk = s_bid[jA - 1];
            if (bk != 0u) {
                const int w = (int)(bk & 0xFFu);
                float m1w = s_rm1[w - 1], m2w = s_rm2[w - 1];
                vA -= (m2w - m1w) + EPS;
                s_v[jA - 1] = vA;
                int old = pA; pA = w;
                s_x[w - 1] = jA;
                s_u[w - 1] = m2w + EPS;
                if (old) s_x[old - 1] = 0;
            }
        }
        {
            unsigned bk = s_bid[jB - 1];
            if (bk != 0u) {
                const int w = (int)(bk & 0xFFu);
                float m1w = s_rm1[w - 1], m2w = s_rm2[w - 1];
                vB -= (m2w - m1w) + EPS;
                s_v[jB - 1] = vB;
                int old = pB; pB = w;
                s_x[w - 1] = jB;
                s_u[w - 1] = m2w + EPS;
                if (old) s_x[old - 1] = 0;
            }
        }
    }

    // load post-auction row state into registers
    uA = s_u[rA - 1]; uB = s_u[rB - 1];
    u64 mA = __ballot(s_x[rA - 1] == 0);   // bit l: row l+1 free
    u64 mB = __ballot(s_x[rB - 1] == 0);   // bit l: row l+65 free
    u64 dA = 0ull, dB = 0ull;

    // ---- Phase B2: serial ARR for leftovers (tie-skip, clamped duals) -----
    int steps = 0;
    while ((mA | mB) != 0ull && steps < ARR_CAP) {
        ++steps;
        const int i0 = mA ? (__builtin_ctzll(mA) + 1) : (__builtin_ctzll(mB) + 65);
        const bool hi = (i0 > 64);
        const int sl = (i0 - 1) & 63;
        const int ri0 = i0 - 1;
        const int a = ri0 * 64 + (lane ^ (ri0 & 31));

        const float rjA = s_costA[a] - vA;
        const float rjB = s_costB[a] - vB;

        unsigned k1 = f2key_arr(rjA, pA != 0, jA);
        unsigned k2 = f2key_arr(rjB, pB != 0, jB);
        if (k2 < k1) { unsigned t = k1; k1 = k2; k2 = t; }
        wave_min2_32(k1, k2);

        const int j1 = (int)(__builtin_amdgcn_readfirstlane(k1) & 0xFFu);
        const int j2 = (int)(__builtin_amdgcn_readfirstlane(k2) & 0xFFu);
        const bool h1 = (j1 > 64); const int s1 = (j1 - 1) & 63;
        const bool h2 = (j2 > 64); const int s2 = (j2 - 1) & 63;
        const float m1 = rl_f(h1 ? rjB : rjA, s1);
        const float m2 = rl_f(h2 ? rjB : rjA, s2);
        const int kdisp = rl_i(h1 ? pB : pA, s1);

        if (hi) mB &= ~(1ull << sl); else mA &= ~(1ull << sl);

        if (kdisp != 0 && !(m2 > m1)) {
            if (hi) dB |= (1ull << sl); else dA |= (1ull << sl);
            continue;
        }
        const float dlt = fmaxf(m2 - m1, 0.0f);
        if (jA == j1) { vA -= dlt; pA = i0; }
        if (jB == j1) { vB -= dlt; pB = i0; }
        if (rA == i0) { uA = m2; }
        if (rB == i0) { uB = m2; }
        if (kdisp != 0) {
            if (kdisp > 64) mB |= (1ull << (kdisp - 65)); else mA |= (1ull << (kdisp - 1));
        }
    }
    mA |= dA;
    mB |= dB;

    // ---- Phase C: single-source SAP, shift-trick, LDS-plane rows ----------
    const float INF = 3.4e38f;
    while ((mA | mB) != 0ull) {
        const int f = mA ? (__builtin_ctzll(mA) + 1) : (__builtin_ctzll(mB) + 65);
        if (f <= 64) mA &= ~(1ull << (f - 1)); else mB &= ~(1ull << (f - 65));

        float minvA = INF, minvB = INF;
        int wayA = 0, wayB = 0;
        bool cuA = false, cuB = false;
        float SuseA = 0.0f, SuseB = 0.0f;
        bool rsA = (rA == f), rsB = (rB == f);
        float SsetA = 0.0f, SsetB = 0.0f;
        int j0 = 0;
        int i0 = f;
        float S = 0.0f;

        float u0 = rl_f((f > 64) ? uB : uA, (f - 1) & 63);
        float pre = u0;
        int ri0 = f - 1;
        int a = ri0 * 64 + (lane ^ (ri0 & 31));
        float cA = s_costA[a];
        float cB = s_costB[a];

        for (;;) {
            if (!cuA) { float cur = (cA - pre) - vA; if (cur < minvA) { minvA = cur; wayA = j0; } }
            if (!cuB) { float cur = (cB - pre) - vB; if (cur < minvB) { minvB = cur; wayB = j0; } }

            unsigned k = umin2(f2key(minvA, jA), f2key(minvB, jB));
            k = wave_minkey32(k);

            const int idx = (int)(__builtin_amdgcn_readfirstlane(k) & 0xFFu);
            const bool hij = (idx > 64);
            const int slj = (idx - 1) & 63;
            const float Snew = rl_f(hij ? minvB : minvA, slj);
            i0 = rl_i(hij ? pB : pA, slj);
            j0 = idx;

            if (jA == j0) { cuA = true; SuseA = Snew; minvA = INF; }
            if (jB == j0) { cuB = true; SuseB = Snew; minvB = INF; }
            S = Snew;
            if (i0 == 0) break;

            if (rA == i0) { rsA = true; SsetA = Snew; }
            if (rB == i0) { rsB = true; SsetB = Snew; }
            u0 = rl_f((i0 > 64) ? uB : uA, (i0 - 1) & 63);
            pre = u0 - S;
            ri0 = i0 - 1;
            a = ri0 * 64 + (lane ^ (ri0 & 31));
            cA = s_costA[a];
            cB = s_costB[a];
        }

        if (cuA) vA -= (S - SuseA);
        if (cuB) vB -= (S - SuseB);
        if (rsA) uA += (S - SsetA);
        if (rsB) uB += (S - SsetB);

        // augment along way[] chain
        int j = j0;
        while (j != 0) {
            int j1 = rl_i((j <= 64) ? wayA : wayB, (j - 1) & 63);
            int pnew = (j1 == 0) ? f : rl_i((j1 <= 64) ? pA : pB, (j1 - 1) & 63);
            if (jA == j) pA = pnew;
            if (jB == j) pB = pnew;
            j = j1;
        }
    }

    // ---- SmoothL1 over matched pairs (cols < c) ---------------------------
    double acc = 0.0;
    if (lane < c) {
        float4 prow = s_row[pA - 1];
        acc += (double)(sl1f(prow.x - tAx) + sl1f(prow.y - tAy) + sl1f(prow.z - tAz));
    }
    if (lane + 64 < c) {
        float4 prow = s_row[pB - 1];
        acc += (double)(sl1f(prow.x - tBx) + sl1f(prow.y - tBy) + sl1f(prow.z - tBz));
    }
    for (int off = 1; off < 64; off <<= 1) acc += __shfl_xor(acc, off);
    if (lane == 0) ws_sl1[b] = acc;
}

// ---- BCE / finalize -------------------------------------------------------

__device__ __forceinline__ double bce_term(float p, float t) {
    float logp = fmaxf(logf(p), -100.0f);
    float logq = fmaxf(logf(1.0f - p), -100.0f);
    return (double)(-(t * logp + (1.0f - t) * logq));
}

__global__ __launch_bounds__(256) void bce_exist_kernel(
    const float* __restrict__ pe, const int* __restrict__ te, double* __restrict__ out)
{
    const int tid = threadIdx.x;
    double acc = 0.0;
    for (int i = tid; i < N_EX; i += 256)
        acc += bce_term(pe[i], (float)te[i]);
    for (int off = 1; off < 64; off <<= 1) acc += __shfl_xor(acc, off);
    __shared__ double s[4];
    if ((tid & 63) == 0) s[tid >> 6] = acc;
    __syncthreads();
    if (tid == 0) out[0] = s[0] + s[1] + s[2] + s[3];
}

__global__ __launch_bounds__(256) void bce_edge_kernel(
    const float* __restrict__ p, const float* __restrict__ t, double* __restrict__ out)
{
    const int tid = threadIdx.x;
    double acc = 0.0;
    for (int i = blockIdx.x * 256 + tid; i < N_EDGE; i += 256 * 256)
        acc += bce_term(p[i], t[i]);
    for (int off = 1; off < 64; off <<= 1) acc += __shfl_xor(acc, off);
    __shared__ double s[4];
    if ((tid & 63) == 0) s[tid >> 6] = acc;
    __syncthreads();
    if (tid == 0) out[blockIdx.x] = s[0] + s[1] + s[2] + s[3];
}

__global__ __launch_bounds__(64) void finalize_kernel(
    const double* __restrict__ ws, const int* __restrict__ counts, float* __restrict__ out)
{
    const int lane = threadIdx.x;
    double vsum = ws[lane];
    double csum = (double)counts[lane];
    double edsum = 0.0;
    for (int k = lane; k < 256; k += 64) edsum += ws[128 + k];
    for (int off = 1; off < 64; off <<= 1) {
        vsum  += __shfl_xor(vsum, off);
        csum  += __shfl_xor(csum, off);
        edsum += __shfl_xor(edsum, off);
    }
    if (lane == 0) {
        double vloss  = vsum / (3.0 * csum);
        double eloss  = ws[64] / (double)N_EX;
        double edloss = edsum / (double)N_EDGE;
        double total  = vloss + eloss + edloss;
        out[0] = (float)total;
        out[1] = (float)vloss;
        out[2] = (float)eloss;
        out[3] = (float)edloss;
    }
}

extern "C" void kernel_launch(void* const* d_in, const int* in_sizes, int n_in,
                              void* d_out, int out_size, void* d_ws, size_t ws_size,
                              hipStream_t stream) {
    const float* pv     = (const float*)d_in[0];
    const float* pe     = (const float*)d_in[1];
    const float* pedge  = (const float*)d_in[2];
    const float* tv     = (const float*)d_in[3];
    const int*   te     = (const int*)d_in[4];
    const float* elab   = (const float*)d_in[5];
    const int*   counts = (const int*)d_in[6];
    double* ws = (double*)d_ws;
    float* out = (float*)d_out;

    hipLaunchKernelGGL(hungarian_kernel, dim3(NB), dim3(64), 0, stream, pv, pe, tv, counts, ws);
    hipLaunchKernelGGL(bce_exist_kernel, dim3(1), dim3(256), 0, stream, pe, te, ws + 64);
    hipLaunchKernelGGL(bce_edge_kernel, dim3(256), dim3(256), 0, stream, pedge, elab, ws + 128);
    hipLaunchKernelGGL(finalize_kernel, dim3(1), dim3(64), 0, stream, ws, counts, out);
}

// Round 13
// 886.821 us; speedup vs baseline: 2.0731x; 2.0731x over previous
//
#include <hip/hip_runtime.h>
#include <math.h>

#define NB 64
#define NV 128
#define NEDGE_PER 8128
#define N_EDGE (NB * NEDGE_PER)   // 520192
#define N_EX (NB * NV)            // 8192
#define BID_ROUNDS 64
#define ARR_CAP 128

// workspace layout (doubles):
// ws[0..63]    per-sample SmoothL1 sums
// ws[64]       existence BCE sum
// ws[128..383] edge BCE partials (256 blocks)

typedef unsigned long long u64;
typedef unsigned int uint2v __attribute__((ext_vector_type(2)));

__device__ __forceinline__ float sl1f(float d) {
    d = fabsf(d);
    return d < 1.0f ? 0.5f * d * d : d - 0.5f;
}
__device__ __forceinline__ unsigned umin2(unsigned a, unsigned b) { return a < b ? a : b; }

// ---- cross-lane helpers ---------------------------------------------------

template <int CTRL>
__device__ __forceinline__ int dpp_i(int x) {
    return __builtin_amdgcn_update_dpp(0, x, CTRL, 0xF, 0xF, true);
}

// Monotone u32 key of f32; low 8 bits = column idx (1..128). Exact ties break
// to lowest idx; exact f32 minv is re-read from the winning lane so duals stay
// accurate. Sub-quantum mis-picks only swap near-optimal alternates.
__device__ __forceinline__ unsigned f2key(float x, int idx) {
    unsigned b = __float_as_uint(x);
    unsigned m = (unsigned)(((int)b) >> 31) | 0x80000000u;
    return ((b ^ m) & ~0xFFu) | (unsigned)idx;
}
// ARR key: bit 8 = assigned-flag (prefer unassigned among ties).
__device__ __forceinline__ unsigned f2key_arr(float x, bool assigned, int idx) {
    unsigned b = __float_as_uint(x);
    unsigned m = (unsigned)(((int)b) >> 31) | 0x80000000u;
    return ((b ^ m) & ~0x1FFu) | (assigned ? 0x100u : 0u) | (unsigned)idx;
}
// bid key: monotone map of bid >= 0, low 8 bits = row idx; max-reduce. >0 always.
__device__ __forceinline__ unsigned bidkey(float b, int row) {
    return ((__float_as_uint(b) | 0x80000000u) & ~0xFFu) | (unsigned)row;
}

// 64-lane min over 32-bit packed keys, broadcast to all lanes.
__device__ __forceinline__ unsigned wave_minkey32(unsigned k) {
    { unsigned o = (unsigned)dpp_i<0xB1>((int)k);  k = umin2(k, o); }
    { unsigned o = (unsigned)dpp_i<0x4E>((int)k);  k = umin2(k, o); }
    { unsigned o = (unsigned)dpp_i<0x141>((int)k); k = umin2(k, o); }
    { unsigned o = (unsigned)dpp_i<0x140>((int)k); k = umin2(k, o); }
#if __has_builtin(__builtin_amdgcn_permlane16_swap)
    { uint2v r = __builtin_amdgcn_permlane16_swap(k, k, false, false);
      k = umin2(k, umin2(r.x, r.y)); }
#else
    { k = umin2(k, (unsigned)__shfl_xor((int)k, 16)); }
#endif
#if __has_builtin(__builtin_amdgcn_permlane32_swap)
    { uint2v r = __builtin_amdgcn_permlane32_swap(k, k, false, false);
      k = umin2(k, umin2(r.x, r.y)); }
#else
    { k = umin2(k, (unsigned)__shfl_xor((int)k, 32)); }
#endif
    return k;
}

// two-smallest merge; requires k1<=k2 and o1<=o2 (self-pair merge harmless).
__device__ __forceinline__ void min2m(unsigned& k1, unsigned& k2, unsigned o1, unsigned o2) {
    if (k1 <= o1) {
        k2 = umin2(k2, o1);
    } else {
        k2 = umin2(o2, k1);
        k1 = o1;
    }
}
// 64-lane (min, 2nd-min) over per-lane sorted pairs; broadcast.
__device__ __forceinline__ void wave_min2_32(unsigned& k1, unsigned& k2) {
    { unsigned o1 = (unsigned)dpp_i<0xB1>((int)k1),  o2 = (unsigned)dpp_i<0xB1>((int)k2);  min2m(k1, k2, o1, o2); }
    { unsigned o1 = (unsigned)dpp_i<0x4E>((int)k1),  o2 = (unsigned)dpp_i<0x4E>((int)k2);  min2m(k1, k2, o1, o2); }
    { unsigned o1 = (unsigned)dpp_i<0x141>((int)k1), o2 = (unsigned)dpp_i<0x141>((int)k2); min2m(k1, k2, o1, o2); }
    { unsigned o1 = (unsigned)dpp_i<0x140>((int)k1), o2 = (unsigned)dpp_i<0x140>((int)k2); min2m(k1, k2, o1, o2); }
#if __has_builtin(__builtin_amdgcn_permlane16_swap)
    { uint2v r1 = __builtin_amdgcn_permlane16_swap(k1, k1, false, false);
      uint2v r2 = __builtin_amdgcn_permlane16_swap(k2, k2, false, false);
      min2m(k1, k2, r1.x, r2.x); min2m(k1, k2, r1.y, r2.y); }
#else
    { unsigned o1 = (unsigned)__shfl_xor((int)k1, 16), o2 = (unsigned)__shfl_xor((int)k2, 16); min2m(k1, k2, o1, o2); }
#endif
#if __has_builtin(__builtin_amdgcn_permlane32_swap)
    { uint2v r1 = __builtin_amdgcn_permlane32_swap(k1, k1, false, false);
      uint2v r2 = __builtin_amdgcn_permlane32_swap(k2, k2, false, false);
      min2m(k1, k2, r1.x, r2.x); min2m(k1, k2, r1.y, r2.y); }
#else
    { unsigned o1 = (unsigned)__shfl_xor((int)k1, 32), o2 = (unsigned)__shfl_xor((int)k2, 32); min2m(k1, k2, o1, o2); }
#endif
}

__device__ __forceinline__ int rl_i(int v, int sl) {
    return __builtin_amdgcn_readlane(v, sl);
}
__device__ __forceinline__ float rl_f(float v, int sl) {
    return __int_as_float(__builtin_amdgcn_readlane(__float_as_int(v), sl));
}

// ---- Hungarian: swizzled cost planes + colred + auction + ARR + SAP
//      (r8 structure + Phase-C runner-up row prefetch) ----------------------

// cost plane layout: entry (0-based row r, 0-based col-half c0) stored at
// r*64 + (c0 ^ (r&31)) -> 2-way banks for both row-broadcast and row-scan.

__global__ __launch_bounds__(64, 1) void hungarian_kernel(
    const float* __restrict__ pv,     // [B,V,3]
    const float* __restrict__ pe,     // [B,V]
    const float* __restrict__ tv,     // [B,V,3]
    const int*   __restrict__ counts, // [B]
    double* __restrict__ ws_sl1)      // [B]
{
    const int b = blockIdx.x;
    const int lane = threadIdx.x;
    const int c = counts[b];

    __shared__ float  s_costA[NV * 64];  // cols 1..64   (32 KB, swizzled)
    __shared__ float  s_costB[NV * 64];  // cols 65..128 (32 KB, swizzled)
    __shared__ float4 s_row[NV];
    __shared__ float  s_pe[NV];
    __shared__ float  s_v[NV];           // column potentials (LDS master copy)
    __shared__ float  s_u[NV];           // row potentials
    __shared__ int    s_x[NV];           // row -> col (0 = free)
    __shared__ float  s_rm1[NV], s_rm2[NV];
    __shared__ unsigned s_bid[NV];

    const float* pvb = pv + (size_t)b * NV * 3;
    const float* peb = pe + (size_t)b * NV;
    const float* tvb = tv + (size_t)b * NV * 3;

    // lane owns rows/cols (1-based): rA=jA=lane+1, rB=jB=lane+65
    {
        float x0 = pvb[lane * 3 + 0], y0 = pvb[lane * 3 + 1], z0 = pvb[lane * 3 + 2];
        float x1 = pvb[(lane + 64) * 3 + 0], y1 = pvb[(lane + 64) * 3 + 1], z1 = pvb[(lane + 64) * 3 + 2];
        float e0 = peb[lane], e1 = peb[lane + 64];
        s_row[lane]      = make_float4(x0, y0, z0, fabsf(e0 - 1.0f));
        s_row[lane + 64] = make_float4(x1, y1, z1, fabsf(e1 - 1.0f));
        s_pe[lane]       = e0;
        s_pe[lane + 64]  = e1;
    }
    const float tAx = tvb[lane * 3 + 0], tAy = tvb[lane * 3 + 1], tAz = tvb[lane * 3 + 2];
    const float tBx = tvb[(lane + 64) * 3 + 0], tBy = tvb[(lane + 64) * 3 + 1], tBz = tvb[(lane + 64) * 3 + 2];

    const int jA = lane + 1, jB = lane + 65;
    const int rA = lane + 1, rB = lane + 65;
    const bool realA = (jA <= c), realB = (jB <= c);

    __syncthreads();

    // ---- Phase 0: build swizzled cost planes (f32-exact, reference order) --
    #pragma unroll 4
    for (int r = 0; r < NV; ++r) {
        float4 row = s_row[r];
        float per = s_pe[r];
        float cAv = realA ? (((fabsf(row.x - tAx) + fabsf(row.y - tAy)) + fabsf(row.z - tAz)) + row.w) : per;
        float cBv = realB ? (((fabsf(row.x - tBx) + fabsf(row.y - tBy)) + fabsf(row.z - tBz)) + row.w) : per;
        const int a = r * 64 + (lane ^ (r & 31));
        s_costA[a] = cAv;
        s_costB[a] = cBv;
    }
    __syncthreads();

    // ---- Phase A: column reduction (v[j] = min_i C[i][j]) -----------------
    float bestA = 3.4e38f, bestB = 3.4e38f;
    #pragma unroll 4
    for (int r = 0; r < NV; ++r) {
        const int a = r * 64 + (lane ^ (r & 31));
        bestA = fminf(bestA, s_costA[a]);
        bestB = fminf(bestB, s_costB[a]);
    }
    float vA = bestA, vB = bestB;   // this lane's column potentials
    float uA = 0.0f, uB = 0.0f;
    int pA = 0, pB = 0;             // col -> row (0 = free)
    s_v[jA - 1] = vA; s_v[jB - 1] = vB;
    s_x[rA - 1] = 0;  s_x[rB - 1] = 0;
    s_u[rA - 1] = 0.0f; s_u[rB - 1] = 0.0f;

    // ---- Phase B: Jacobi auction rounds (parallel row bids, zero-eps) -----
    int prevFree = NV + 1, stall = 0;
    for (int round = 0; round < BID_ROUNDS; ++round) {
        const int xAcur = s_x[rA - 1];
        const int xBcur = s_x[rB - 1];
        const u64 fA = __ballot(xAcur == 0);
        const u64 fB = __ballot(xBcur == 0);
        const int nfree = __popcll(fA) + __popcll(fB);
        if (nfree == 0 || nfree <= 8) break;
        if (nfree >= prevFree) { if (++stall >= 2) break; } else stall = 0;
        prevFree = nfree;

        s_bid[jA - 1] = 0u;
        s_bid[jB - 1] = 0u;

        // scan my free rows (exact f32 min/second-min, rotated tie-break)
        #pragma unroll
        for (int half = 0; half < 2; ++half) {
            const int ri = (half == 0) ? rA : rB;            // 1-based row
            const int xcur = (half == 0) ? xAcur : xBcur;
            if (xcur != 0) continue;
            const int r0 = ri - 1;
            const int swz = r0 & 31;
            float m1 = 3.4e38f, m2 = 3.4e38f;
            int j1 = 0, rot1 = 1000;
            #pragma unroll 4
            for (int j0 = 0; j0 < 64; ++j0) {
                const int a = r0 * 64 + (j0 ^ swz);
                float ca = s_costA[a] - s_v[j0];
                float cb = s_costB[a] - s_v[j0 + 64];
                int rotA = (j0 + 1 - ri) & 127;
                int rotB = (j0 + 65 - ri) & 127;
                if (ca < m1 || (ca == m1 && rotA < rot1)) { m2 = m1; m1 = ca; j1 = j0 + 1; rot1 = rotA; }
                else if (ca < m2) m2 = ca;
                if (cb < m1 || (cb == m1 && rotB < rot1)) { m2 = m1; m1 = cb; j1 = j0 + 65; rot1 = rotB; }
                else if (cb < m2) m2 = cb;
            }
            s_rm1[r0] = m1;
            s_rm2[r0] = m2;
            atomicMax(&s_bid[j1 - 1], bidkey(m2 - m1, ri));
        }

        // column accept (this lane's two columns)
        {
            unsigned bk = s_bid[jA - 1];
            if (bk != 0u) {
                const int w = (int)(bk & 0xFFu);
                float m1w = s_rm1[w - 1], m2w = s_rm2[w - 1];
                vA -= (m2w - m1w);
                s_v[jA - 1] = vA;
                int old = pA; pA = w;
                s_x[w - 1] = jA;
                s_u[w - 1] = m2w;
                if (old) s_x[old - 1] = 0;
            }
        }
        {
            unsigned bk = s_bid[jB - 1];
            if (bk != 0u) {
                const int w = (int)(bk & 0xFFu);
                float m1w = s_rm1[w - 1], m2w = s_rm2[w - 1];
                vB -= (m2w - m1w);
                s_v[jB - 1] = vB;
                int old = pB; pB = w;
                s_x[w - 1] = jB;
                s_u[w - 1] = m2w;
                if (old) s_x[old - 1] = 0;
            }
        }
    }

    // load post-auction row state into registers
    uA = s_u[rA - 1]; uB = s_u[rB - 1];
    u64 mA = __ballot(s_x[rA - 1] == 0);   // bit l: row l+1 free
    u64 mB = __ballot(s_x[rB - 1] == 0);   // bit l: row l+65 free
    u64 dA = 0ull, dB = 0ull;

    // ---- Phase B2: serial ARR for leftovers (tie-skip, clamped duals) -----
    int steps = 0;
    while ((mA | mB) != 0ull && steps < ARR_CAP) {
        ++steps;
        const int i0 = mA ? (__builtin_ctzll(mA) + 1) : (__builtin_ctzll(mB) + 65);
        const bool hi = (i0 > 64);
        const int sl = (i0 - 1) & 63;
        const int ri0 = i0 - 1;
        const int a = ri0 * 64 + (lane ^ (ri0 & 31));

        const float rjA = s_costA[a] - vA;
        const float rjB = s_costB[a] - vB;

        unsigned k1 = f2key_arr(rjA, pA != 0, jA);
        unsigned k2 = f2key_arr(rjB, pB != 0, jB);
        if (k2 < k1) { unsigned t = k1; k1 = k2; k2 = t; }
        wave_min2_32(k1, k2);

        const int j1 = (int)(__builtin_amdgcn_readfirstlane(k1) & 0xFFu);
        const int j2 = (int)(__builtin_amdgcn_readfirstlane(k2) & 0xFFu);
        const bool h1 = (j1 > 64); const int s1 = (j1 - 1) & 63;
        const bool h2 = (j2 > 64); const int s2 = (j2 - 1) & 63;
        const float m1 = rl_f(h1 ? rjB : rjA, s1);
        const float m2 = rl_f(h2 ? rjB : rjA, s2);
        const int kdisp = rl_i(h1 ? pB : pA, s1);

        if (hi) mB &= ~(1ull << sl); else mA &= ~(1ull << sl);

        if (kdisp != 0 && !(m2 > m1)) {
            if (hi) dB |= (1ull << sl); else dA |= (1ull << sl);
            continue;
        }
        const float dlt = fmaxf(m2 - m1, 0.0f);
        if (jA == j1) { vA -= dlt; pA = i0; }
        if (jB == j1) { vB -= dlt; pB = i0; }
        if (rA == i0) { uA = m2; }
        if (rB == i0) { uB = m2; }
        if (kdisp != 0) {
            if (kdisp > 64) mB |= (1ull << (kdisp - 65)); else mA |= (1ull << (kdisp - 1));
        }
    }
    mA |= dA;
    mB |= dB;

    // ---- Phase C: single-source SAP, shift-trick, runner-up row prefetch --
    // wave_min2 gives winner j1 and runner-up j2; the NEXT settle is usually
    // j2, so prefetch row p[j2] (issued ~190cy before potential use). p[] is
    // invariant during a search, so reused row data is bit-identical.
    const float INF = 3.4e38f;
    while ((mA | mB) != 0ull) {
        const int f = mA ? (__builtin_ctzll(mA) + 1) : (__builtin_ctzll(mB) + 65);
        if (f <= 64) mA &= ~(1ull << (f - 1)); else mB &= ~(1ull << (f - 65));

        float minvA = INF, minvB = INF;
        int wayA = 0, wayB = 0;
        bool cuA = false, cuB = false;
        float SuseA = 0.0f, SuseB = 0.0f;
        bool rsA = (rA == f), rsB = (rB == f);
        float SsetA = 0.0f, SsetB = 0.0f;
        int j0 = 0;
        float S = 0.0f;

        float u0 = rl_f((f > 64) ? uB : uA, (f - 1) & 63);
        float pre = u0;
        int ri0 = f - 1;
        int a = ri0 * 64 + (lane ^ (ri0 & 31));
        float cA = s_costA[a];
        float cB = s_costB[a];

        int pfCol = 0;              // column whose matched row is cached
        float pfCA = 0.0f, pfCB = 0.0f;

        for (;;) {
            if (!cuA) { float cur = (cA - pre) - vA; if (cur < minvA) { minvA = cur; wayA = j0; } }
            if (!cuB) { float cur = (cB - pre) - vB; if (cur < minvB) { minvB = cur; wayB = j0; } }

            unsigned k1 = cuA ? 0xFFFFFFFFu : f2key(minvA, jA);
            unsigned k2 = cuB ? 0xFFFFFFFFu : f2key(minvB, jB);
            if (k2 < k1) { unsigned t = k1; k1 = k2; k2 = t; }
            wave_min2_32(k1, k2);

            const unsigned k1s = __builtin_amdgcn_readfirstlane(k1);
            const unsigned k2s = __builtin_amdgcn_readfirstlane(k2);
            const int idx = (int)(k1s & 0xFFu);
            const bool hij = (idx > 64);
            const int slj = (idx - 1) & 63;
            const float Snew = rl_f(hij ? minvB : minvA, slj);
            const int i0 = rl_i(hij ? pB : pA, slj);
            j0 = idx;

            if (jA == j0) { cuA = true; SuseA = Snew; minvA = INF; }
            if (jB == j0) { cuB = true; SuseB = Snew; minvB = INF; }
            S = Snew;
            if (i0 == 0) break;

            if (rA == i0) { rsA = true; SsetA = Snew; }
            if (rB == i0) { rsB = true; SsetB = Snew; }

            // row data for i0: speculation hit if prev runner-up == winner
            if (j0 == pfCol) {
                cA = pfCA; cB = pfCB;
            } else {
                ri0 = i0 - 1;
                a = ri0 * 64 + (lane ^ (ri0 & 31));
                cA = s_costA[a];
                cB = s_costB[a];
            }
            // prefetch this round's runner-up row (off critical path)
            pfCol = 0;
            const int idx2 = (int)(k2s & 0xFFu);
            if (k2s != 0xFFFFFFFFu && idx2 >= 1 && idx2 <= NV && idx2 != j0) {
                const int i2 = rl_i((idx2 > 64) ? pB : pA, (idx2 - 1) & 63);
                if (i2 != 0) {
                    const int ri2 = i2 - 1;
                    const int a2 = ri2 * 64 + (lane ^ (ri2 & 31));
                    pfCA = s_costA[a2];
                    pfCB = s_costB[a2];
                    pfCol = idx2;
                }
            }
            u0 = rl_f((i0 > 64) ? uB : uA, (i0 - 1) & 63);
            pre = u0 - S;
        }

        if (cuA) vA -= (S - SuseA);
        if (cuB) vB -= (S - SuseB);
        if (rsA) uA += (S - SsetA);
        if (rsB) uB += (S - SsetB);

        // augment along way[] chain
        int j = j0;
        while (j != 0) {
            int j1 = rl_i((j <= 64) ? wayA : wayB, (j - 1) & 63);
            int pnew = (j1 == 0) ? f : rl_i((j1 <= 64) ? pA : pB, (j1 - 1) & 63);
            if (jA == j) pA = pnew;
            if (jB == j) pB = pnew;
            j = j1;
        }
    }

    // ---- SmoothL1 over matched pairs (cols < c) ---------------------------
    double acc = 0.0;
    if (lane < c) {
        float4 prow = s_row[pA - 1];
        acc += (double)(sl1f(prow.x - tAx) + sl1f(prow.y - tAy) + sl1f(prow.z - tAz));
    }
    if (lane + 64 < c) {
        float4 prow = s_row[pB - 1];
        acc += (double)(sl1f(prow.x - tBx) + sl1f(prow.y - tBy) + sl1f(prow.z - tBz));
    }
    for (int off = 1; off < 64; off <<= 1) acc += __shfl_xor(acc, off);
    if (lane == 0) ws_sl1[b] = acc;
}

// ---- BCE / finalize -------------------------------------------------------

__device__ __forceinline__ double bce_term(float p, float t) {
    float logp = fmaxf(logf(p), -100.0f);
    float logq = fmaxf(logf(1.0f - p), -100.0f);
    return (double)(-(t * logp + (1.0f - t) * logq));
}

__global__ __launch_bounds__(256) void bce_exist_kernel(
    const float* __restrict__ pe, const int* __restrict__ te, double* __restrict__ out)
{
    const int tid = threadIdx.x;
    double acc = 0.0;
    for (int i = tid; i < N_EX; i += 256)
        acc += bce_term(pe[i], (float)te[i]);
    for (int off = 1; off < 64; off <<= 1) acc += __shfl_xor(acc, off);
    __shared__ double s[4];
    if ((tid & 63) == 0) s[tid >> 6] = acc;
    __syncthreads();
    if (tid == 0) out[0] = s[0] + s[1] + s[2] + s[3];
}

__global__ __launch_bounds__(256) void bce_edge_kernel(
    const float* __restrict__ p, const float* __restrict__ t, double* __restrict__ out)
{
    const int tid = threadIdx.x;
    double acc = 0.0;
    for (int i = blockIdx.x * 256 + tid; i < N_EDGE; i += 256 * 256)
        acc += bce_term(p[i], t[i]);
    for (int off = 1; off < 64; off <<= 1) acc += __shfl_xor(acc, off);
    __shared__ double s[4];
    if ((tid & 63) == 0) s[tid >> 6] = acc;
    __syncthreads();
    if (tid == 0) out[blockIdx.x] = s[0] + s[1] + s[2] + s[3];
}

__global__ __launch_bounds__(64) void finalize_kernel(
    const double* __restrict__ ws, const int* __restrict__ counts, float* __restrict__ out)
{
    const int lane = threadIdx.x;
    double vsum = ws[lane];
    double csum = (double)counts[lane];
    double edsum = 0.0;
    for (int k = lane; k < 256; k += 64) edsum += ws[128 + k];
    for (int off = 1; off < 64; off <<= 1) {
        vsum  += __shfl_xor(vsum, off);
        csum  += __shfl_xor(csum, off);
        edsum += __shfl_xor(edsum, off);
    }
    if (lane == 0) {
        double vloss  = vsum / (3.0 * csum);
        double eloss  = ws[64] / (double)N_EX;
        double edloss = edsum / (double)N_EDGE;
        double total  = vloss + eloss + edloss;
        out[0] = (float)total;
        out[1] = (float)vloss;
        out[2] = (float)eloss;
        out[3] = (float)edloss;
    }
}

extern "C" void kernel_launch(void* const* d_in, const int* in_sizes, int n_in,
                              void* d_out, int out_size, void* d_ws, size_t ws_size,
                              hipStream_t stream) {
    const float* pv     = (const float*)d_in[0];
    const float* pe     = (const float*)d_in[1];
    const float* pedge  = (const float*)d_in[2];
    const float* tv     = (const float*)d_in[3];
    const int*   te     = (const int*)d_in[4];
    const float* elab   = (const float*)d_in[5];
    const int*   counts = (const int*)d_in[6];
    double* ws = (double*)d_ws;
    float* out = (float*)d_out;

    hipLaunchKernelGGL(hungarian_kernel, dim3(NB), dim3(64), 0, stream, pv, pe, tv, counts, ws);
    hipLaunchKernelGGL(bce_exist_kernel, dim3(1), dim3(256), 0, stream, pe, te, ws + 64);
    hipLaunchKernelGGL(bce_edge_kernel, dim3(256), dim3(256), 0, stream, pedge, elab, ws + 128);
    hipLaunchKernelGGL(finalize_kernel, dim3(1), dim3(64), 0, stream, ws, counts, out);
}

// Round 14
// 655.133 us; speedup vs baseline: 2.8063x; 1.3536x over previous
//
#include <hip/hip_runtime.h>
#include <math.h>

#define NB 64
#define NV 128
#define NEDGE_PER 8128
#define N_EDGE (NB * NEDGE_PER)   // 520192
#define N_EX (NB * NV)            // 8192
#define BID_ROUNDS 64
#define ARR_CAP 128

// workspace layout (doubles):
// ws[0..63]    per-sample SmoothL1 sums
// ws[64]       existence BCE sum
// ws[128..383] edge BCE partials (256 blocks)

typedef unsigned long long u64;
typedef unsigned int uint2v __attribute__((ext_vector_type(2)));

__device__ __forceinline__ float sl1f(float d) {
    d = fabsf(d);
    return d < 1.0f ? 0.5f * d * d : d - 0.5f;
}
__device__ __forceinline__ unsigned umin2(unsigned a, unsigned b) { return a < b ? a : b; }

// ---- cross-lane helpers ---------------------------------------------------

template <int CTRL>
__device__ __forceinline__ int dpp_i(int x) {
    return __builtin_amdgcn_update_dpp(0, x, CTRL, 0xF, 0xF, true);
}

// Monotone u32 key of f32; low 8 bits = column idx (1..128). Exact ties break
// to lowest idx; exact f32 minv is re-read from the winning lane so duals stay
// accurate. Sub-quantum mis-picks only swap near-optimal alternates.
__device__ __forceinline__ unsigned f2key(float x, int idx) {
    unsigned b = __float_as_uint(x);
    unsigned m = (unsigned)(((int)b) >> 31) | 0x80000000u;
    return ((b ^ m) & ~0xFFu) | (unsigned)idx;
}
// ARR key: bit 8 = assigned-flag (prefer unassigned among ties).
__device__ __forceinline__ unsigned f2key_arr(float x, bool assigned, int idx) {
    unsigned b = __float_as_uint(x);
    unsigned m = (unsigned)(((int)b) >> 31) | 0x80000000u;
    return ((b ^ m) & ~0x1FFu) | (assigned ? 0x100u : 0u) | (unsigned)idx;
}
// bid key: monotone map of bid >= 0, low 8 bits = row idx; max-reduce. >0 always.
__device__ __forceinline__ unsigned bidkey(float b, int row) {
    return ((__float_as_uint(b) | 0x80000000u) & ~0xFFu) | (unsigned)row;
}

// 64-lane min over 32-bit packed keys, broadcast to all lanes.
__device__ __forceinline__ unsigned wave_minkey32(unsigned k) {
    { unsigned o = (unsigned)dpp_i<0xB1>((int)k);  k = umin2(k, o); }
    { unsigned o = (unsigned)dpp_i<0x4E>((int)k);  k = umin2(k, o); }
    { unsigned o = (unsigned)dpp_i<0x141>((int)k); k = umin2(k, o); }
    { unsigned o = (unsigned)dpp_i<0x140>((int)k); k = umin2(k, o); }
#if __has_builtin(__builtin_amdgcn_permlane16_swap)
    { uint2v r = __builtin_amdgcn_permlane16_swap(k, k, false, false);
      k = umin2(k, umin2(r.x, r.y)); }
#else
    { k = umin2(k, (unsigned)__shfl_xor((int)k, 16)); }
#endif
#if __has_builtin(__builtin_amdgcn_permlane32_swap)
    { uint2v r = __builtin_amdgcn_permlane32_swap(k, k, false, false);
      k = umin2(k, umin2(r.x, r.y)); }
#else
    { k = umin2(k, (unsigned)__shfl_xor((int)k, 32)); }
#endif
    return k;
}

// two-smallest merge; requires k1<=k2 and o1<=o2 (self-pair merge harmless).
__device__ __forceinline__ void min2m(unsigned& k1, unsigned& k2, unsigned o1, unsigned o2) {
    if (k1 <= o1) {
        k2 = umin2(k2, o1);
    } else {
        k2 = umin2(o2, k1);
        k1 = o1;
    }
}
// 64-lane (min, 2nd-min) over per-lane sorted pairs; broadcast.
__device__ __forceinline__ void wave_min2_32(unsigned& k1, unsigned& k2) {
    { unsigned o1 = (unsigned)dpp_i<0xB1>((int)k1),  o2 = (unsigned)dpp_i<0xB1>((int)k2);  min2m(k1, k2, o1, o2); }
    { unsigned o1 = (unsigned)dpp_i<0x4E>((int)k1),  o2 = (unsigned)dpp_i<0x4E>((int)k2);  min2m(k1, k2, o1, o2); }
    { unsigned o1 = (unsigned)dpp_i<0x141>((int)k1), o2 = (unsigned)dpp_i<0x141>((int)k2); min2m(k1, k2, o1, o2); }
    { unsigned o1 = (unsigned)dpp_i<0x140>((int)k1), o2 = (unsigned)dpp_i<0x140>((int)k2); min2m(k1, k2, o1, o2); }
#if __has_builtin(__builtin_amdgcn_permlane16_swap)
    { uint2v r1 = __builtin_amdgcn_permlane16_swap(k1, k1, false, false);
      uint2v r2 = __builtin_amdgcn_permlane16_swap(k2, k2, false, false);
      min2m(k1, k2, r1.x, r2.x); min2m(k1, k2, r1.y, r2.y); }
#else
    { unsigned o1 = (unsigned)__shfl_xor((int)k1, 16), o2 = (unsigned)__shfl_xor((int)k2, 16); min2m(k1, k2, o1, o2); }
#endif
#if __has_builtin(__builtin_amdgcn_permlane32_swap)
    { uint2v r1 = __builtin_amdgcn_permlane32_swap(k1, k1, false, false);
      uint2v r2 = __builtin_amdgcn_permlane32_swap(k2, k2, false, false);
      min2m(k1, k2, r1.x, r2.x); min2m(k1, k2, r1.y, r2.y); }
#else
    { unsigned o1 = (unsigned)__shfl_xor((int)k1, 32), o2 = (unsigned)__shfl_xor((int)k2, 32); min2m(k1, k2, o1, o2); }
#endif
}

__device__ __forceinline__ int rl_i(int v, int sl) {
    return __builtin_amdgcn_readlane(v, sl);
}
__device__ __forceinline__ float rl_f(float v, int sl) {
    return __int_as_float(__builtin_amdgcn_readlane(__float_as_int(v), sl));
}

// ---- Hungarian: swizzled cost planes + colred + auction + ARR + SAP -------

// cost plane layout: entry (0-based row r, 0-based col-half c0) stored at
// r*64 + (c0 ^ (r&31)) -> 2-way banks for both row-broadcast and row-scan.

__global__ __launch_bounds__(64, 1) void hungarian_kernel(
    const float* __restrict__ pv,     // [B,V,3]
    const float* __restrict__ pe,     // [B,V]
    const float* __restrict__ tv,     // [B,V,3]
    const int*   __restrict__ counts, // [B]
    double* __restrict__ ws_sl1)      // [B]
{
    const int b = blockIdx.x;
    const int lane = threadIdx.x;
    const int c = counts[b];

    __shared__ float  s_costA[NV * 64];  // cols 1..64   (32 KB, swizzled)
    __shared__ float  s_costB[NV * 64];  // cols 65..128 (32 KB, swizzled)
    __shared__ float4 s_row[NV];
    __shared__ float  s_pe[NV];
    __shared__ float  s_v[NV];           // column potentials (LDS master copy)
    __shared__ float  s_u[NV];           // row potentials
    __shared__ int    s_x[NV];           // row -> col (0 = free)
    __shared__ float  s_rm1[NV], s_rm2[NV];
    __shared__ unsigned s_bid[NV];

    const float* pvb = pv + (size_t)b * NV * 3;
    const float* peb = pe + (size_t)b * NV;
    const float* tvb = tv + (size_t)b * NV * 3;

    // lane owns rows/cols (1-based): rA=jA=lane+1, rB=jB=lane+65
    {
        float x0 = pvb[lane * 3 + 0], y0 = pvb[lane * 3 + 1], z0 = pvb[lane * 3 + 2];
        float x1 = pvb[(lane + 64) * 3 + 0], y1 = pvb[(lane + 64) * 3 + 1], z1 = pvb[(lane + 64) * 3 + 2];
        float e0 = peb[lane], e1 = peb[lane + 64];
        s_row[lane]      = make_float4(x0, y0, z0, fabsf(e0 - 1.0f));
        s_row[lane + 64] = make_float4(x1, y1, z1, fabsf(e1 - 1.0f));
        s_pe[lane]       = e0;
        s_pe[lane + 64]  = e1;
    }
    const float tAx = tvb[lane * 3 + 0], tAy = tvb[lane * 3 + 1], tAz = tvb[lane * 3 + 2];
    const float tBx = tvb[(lane + 64) * 3 + 0], tBy = tvb[(lane + 64) * 3 + 1], tBz = tvb[(lane + 64) * 3 + 2];

    const int jA = lane + 1, jB = lane + 65;
    const int rA = lane + 1, rB = lane + 65;
    const bool realA = (jA <= c), realB = (jB <= c);

    __syncthreads();

    // ---- Phase 0: build swizzled cost planes (f32-exact, reference order) --
    #pragma unroll 4
    for (int r = 0; r < NV; ++r) {
        float4 row = s_row[r];
        float per = s_pe[r];
        float cAv = realA ? (((fabsf(row.x - tAx) + fabsf(row.y - tAy)) + fabsf(row.z - tAz)) + row.w) : per;
        float cBv = realB ? (((fabsf(row.x - tBx) + fabsf(row.y - tBy)) + fabsf(row.z - tBz)) + row.w) : per;
        const int a = r * 64 + (lane ^ (r & 31));
        s_costA[a] = cAv;
        s_costB[a] = cBv;
    }
    __syncthreads();

    // ---- Phase A: column reduction (v[j] = min_i C[i][j]) -----------------
    float bestA = 3.4e38f, bestB = 3.4e38f;
    #pragma unroll 4
    for (int r = 0; r < NV; ++r) {
        const int a = r * 64 + (lane ^ (r & 31));
        bestA = fminf(bestA, s_costA[a]);
        bestB = fminf(bestB, s_costB[a]);
    }
    float vA = bestA, vB = bestB;   // this lane's column potentials
    float uA = 0.0f, uB = 0.0f;
    int pA = 0, pB = 0;             // col -> row (0 = free)
    s_v[jA - 1] = vA; s_v[jB - 1] = vB;
    s_x[rA - 1] = 0;  s_x[rB - 1] = 0;
    s_u[rA - 1] = 0.0f; s_u[rB - 1] = 0.0f;

    // ---- Phase B: Jacobi auction rounds (parallel row bids) ---------------
    // Exact bids (gamma = m2-m1): v only decreases => u+v <= C stays feasible;
    // winner edges exactly tight. Early exits: converged / stragglers-only /
    // price-war stall (no free-count progress 2 rounds).
    int prevFree = NV + 1, stall = 0;
    for (int round = 0; round < BID_ROUNDS; ++round) {
        const int xAcur = s_x[rA - 1];
        const int xBcur = s_x[rB - 1];
        const u64 fA = __ballot(xAcur == 0);
        const u64 fB = __ballot(xBcur == 0);
        const int nfree = __popcll(fA) + __popcll(fB);
        if (nfree == 0 || nfree <= 8) break;
        if (nfree >= prevFree) { if (++stall >= 2) break; } else stall = 0;
        prevFree = nfree;

        s_bid[jA - 1] = 0u;
        s_bid[jB - 1] = 0u;

        // scan my free rows (exact f32 min/second-min, rotated tie-break)
        #pragma unroll
        for (int half = 0; half < 2; ++half) {
            const int ri = (half == 0) ? rA : rB;            // 1-based row
            const int xcur = (half == 0) ? xAcur : xBcur;
            if (xcur != 0) continue;
            const int r0 = ri - 1;
            const int swz = r0 & 31;
            float m1 = 3.4e38f, m2 = 3.4e38f;
            int j1 = 0, rot1 = 1000;
            #pragma unroll 4
            for (int j0 = 0; j0 < 64; ++j0) {
                const int a = r0 * 64 + (j0 ^ swz);
                float ca = s_costA[a] - s_v[j0];
                float cb = s_costB[a] - s_v[j0 + 64];
                int rotA = (j0 + 1 - ri) & 127;
                int rotB = (j0 + 65 - ri) & 127;
                if (ca < m1 || (ca == m1 && rotA < rot1)) { m2 = m1; m1 = ca; j1 = j0 + 1; rot1 = rotA; }
                else if (ca < m2) m2 = ca;
                if (cb < m1 || (cb == m1 && rotB < rot1)) { m2 = m1; m1 = cb; j1 = j0 + 65; rot1 = rotB; }
                else if (cb < m2) m2 = cb;
            }
            s_rm1[r0] = m1;
            s_rm2[r0] = m2;
            atomicMax(&s_bid[j1 - 1], bidkey(m2 - m1, ri));
        }

        // column accept (this lane's two columns)
        {
            unsigned bk = s_bid[jA - 1];
            if (bk != 0u) {
                const int w = (int)(bk & 0xFFu);
                float m1w = s_rm1[w - 1], m2w = s_rm2[w - 1];
                vA -= (m2w - m1w);
                s_v[jA - 1] = vA;
                int old = pA; pA = w;
                s_x[w - 1] = jA;
                s_u[w - 1] = m2w;
                if (old) s_x[old - 1] = 0;
            }
        }
        {
            unsigned bk = s_bid[jB - 1];
            if (bk != 0u) {
                const int w = (int)(bk & 0xFFu);
                float m1w = s_rm1[w - 1], m2w = s_rm2[w - 1];
                vB -= (m2w - m1w);
                s_v[jB - 1] = vB;
                int old = pB; pB = w;
                s_x[w - 1] = jB;
                s_u[w - 1] = m2w;
                if (old) s_x[old - 1] = 0;
            }
        }
    }

    // load post-auction row state into registers
    uA = s_u[rA - 1]; uB = s_u[rB - 1];
    u64 mA = __ballot(s_x[rA - 1] == 0);   // bit l: row l+1 free
    u64 mB = __ballot(s_x[rB - 1] == 0);   // bit l: row l+65 free
    u64 dA = 0ull, dB = 0ull;

    // ---- Phase B2: serial ARR for leftovers (tie-skip, clamped duals) -----
    int steps = 0;
    while ((mA | mB) != 0ull && steps < ARR_CAP) {
        ++steps;
        const int i0 = mA ? (__builtin_ctzll(mA) + 1) : (__builtin_ctzll(mB) + 65);
        const bool hi = (i0 > 64);
        const int sl = (i0 - 1) & 63;
        const int ri0 = i0 - 1;
        const int a = ri0 * 64 + (lane ^ (ri0 & 31));

        const float rjA = s_costA[a] - vA;
        const float rjB = s_costB[a] - vB;

        unsigned k1 = f2key_arr(rjA, pA != 0, jA);
        unsigned k2 = f2key_arr(rjB, pB != 0, jB);
        if (k2 < k1) { unsigned t = k1; k1 = k2; k2 = t; }
        wave_min2_32(k1, k2);

        const int j1 = (int)(__builtin_amdgcn_readfirstlane(k1) & 0xFFu);
        const int j2 = (int)(__builtin_amdgcn_readfirstlane(k2) & 0xFFu);
        const bool h1 = (j1 > 64); const int s1 = (j1 - 1) & 63;
        const bool h2 = (j2 > 64); const int s2 = (j2 - 1) & 63;
        const float m1 = rl_f(h1 ? rjB : rjA, s1);
        const float m2 = rl_f(h2 ? rjB : rjA, s2);
        const int kdisp = rl_i(h1 ? pB : pA, s1);

        if (hi) mB &= ~(1ull << sl); else mA &= ~(1ull << sl);

        if (kdisp != 0 && !(m2 > m1)) {
            if (hi) dB |= (1ull << sl); else dA |= (1ull << sl);
            continue;
        }
        const float dlt = fmaxf(m2 - m1, 0.0f);
        if (jA == j1) { vA -= dlt; pA = i0; }
        if (jB == j1) { vB -= dlt; pB = i0; }
        if (rA == i0) { uA = m2; }
        if (rB == i0) { uB = m2; }
        if (kdisp != 0) {
            if (kdisp > 64) mB |= (1ull << (kdisp - 65)); else mA |= (1ull << (kdisp - 1));
        }
    }
    mA |= dA;
    mB |= dB;

    // ---- Phase C: single-source shortest augmenting paths (shift-trick) ---
    const float INF = 3.4e38f;
    while ((mA | mB) != 0ull) {
        const int f = mA ? (__builtin_ctzll(mA) + 1) : (__builtin_ctzll(mB) + 65);
        if (f <= 64) mA &= ~(1ull << (f - 1)); else mB &= ~(1ull << (f - 65));

        float minvA = INF, minvB = INF;
        int wayA = 0, wayB = 0;
        bool cuA = false, cuB = false;
        float SuseA = 0.0f, SuseB = 0.0f;
        bool rsA = (rA == f), rsB = (rB == f);
        float SsetA = 0.0f, SsetB = 0.0f;
        int j0 = 0;
        int i0 = f;
        float S = 0.0f;

        float u0 = rl_f((f > 64) ? uB : uA, (f - 1) & 63);
        float pre = u0;
        int ri0 = f - 1;
        int a = ri0 * 64 + (lane ^ (ri0 & 31));
        float cA = s_costA[a];
        float cB = s_costB[a];

        for (;;) {
            if (!cuA) { float cur = (cA - pre) - vA; if (cur < minvA) { minvA = cur; wayA = j0; } }
            if (!cuB) { float cur = (cB - pre) - vB; if (cur < minvB) { minvB = cur; wayB = j0; } }

            unsigned k = umin2(f2key(minvA, jA), f2key(minvB, jB));
            k = wave_minkey32(k);

            const int idx = (int)(__builtin_amdgcn_readfirstlane(k) & 0xFFu);
            const bool hij = (idx > 64);
            const int slj = (idx - 1) & 63;
            const float Snew = rl_f(hij ? minvB : minvA, slj);
            i0 = rl_i(hij ? pB : pA, slj);
            j0 = idx;

            if (jA == j0) { cuA = true; SuseA = Snew; minvA = INF; }
            if (jB == j0) { cuB = true; SuseB = Snew; minvB = INF; }
            S = Snew;
            if (i0 == 0) break;

            if (rA == i0) { rsA = true; SsetA = Snew; }
            if (rB == i0) { rsB = true; SsetB = Snew; }
            u0 = rl_f((i0 > 64) ? uB : uA, (i0 - 1) & 63);
            pre = u0 - S;
            ri0 = i0 - 1;
            a = ri0 * 64 + (lane ^ (ri0 & 31));
            cA = s_costA[a];
            cB = s_costB[a];
        }

        if (cuA) vA -= (S - SuseA);
        if (cuB) vB -= (S - SuseB);
        if (rsA) uA += (S - SsetA);
        if (rsB) uB += (S - SsetB);

        // augment along way[] chain
        int j = j0;
        while (j != 0) {
            int j1 = rl_i((j <= 64) ? wayA : wayB, (j - 1) & 63);
            int pnew = (j1 == 0) ? f : rl_i((j1 <= 64) ? pA : pB, (j1 - 1) & 63);
            if (jA == j) pA = pnew;
            if (jB == j) pB = pnew;
            j = j1;
        }
    }

    // ---- SmoothL1 over matched pairs (cols < c) ---------------------------
    double acc = 0.0;
    if (lane < c) {
        float4 prow = s_row[pA - 1];
        acc += (double)(sl1f(prow.x - tAx) + sl1f(prow.y - tAy) + sl1f(prow.z - tAz));
    }
    if (lane + 64 < c) {
        float4 prow = s_row[pB - 1];
        acc += (double)(sl1f(prow.x - tBx) + sl1f(prow.y - tBy) + sl1f(prow.z - tBz));
    }
    for (int off = 1; off < 64; off <<= 1) acc += __shfl_xor(acc, off);
    if (lane == 0) ws_sl1[b] = acc;
}

// ---- BCE / finalize -------------------------------------------------------

__device__ __forceinline__ double bce_term(float p, float t) {
    float logp = fmaxf(logf(p), -100.0f);
    float logq = fmaxf(logf(1.0f - p), -100.0f);
    return (double)(-(t * logp + (1.0f - t) * logq));
}

__global__ __launch_bounds__(256) void bce_exist_kernel(
    const float* __restrict__ pe, const int* __restrict__ te, double* __restrict__ out)
{
    const int tid = threadIdx.x;
    double acc = 0.0;
    for (int i = tid; i < N_EX; i += 256)
        acc += bce_term(pe[i], (float)te[i]);
    for (int off = 1; off < 64; off <<= 1) acc += __shfl_xor(acc, off);
    __shared__ double s[4];
    if ((tid & 63) == 0) s[tid >> 6] = acc;
    __syncthreads();
    if (tid == 0) out[0] = s[0] + s[1] + s[2] + s[3];
}

__global__ __launch_bounds__(256) void bce_edge_kernel(
    const float* __restrict__ p, const float* __restrict__ t, double* __restrict__ out)
{
    const int tid = threadIdx.x;
    double acc = 0.0;
    for (int i = blockIdx.x * 256 + tid; i < N_EDGE; i += 256 * 256)
        acc += bce_term(p[i], t[i]);
    for (int off = 1; off < 64; off <<= 1) acc += __shfl_xor(acc, off);
    __shared__ double s[4];
    if ((tid & 63) == 0) s[tid >> 6] = acc;
    __syncthreads();
    if (tid == 0) out[blockIdx.x] = s[0] + s[1] + s[2] + s[3];
}

__global__ __launch_bounds__(64) void finalize_kernel(
    const double* __restrict__ ws, const int* __restrict__ counts, float* __restrict__ out)
{
    const int lane = threadIdx.x;
    double vsum = ws[lane];
    double csum = (double)counts[lane];
    double edsum = 0.0;
    for (int k = lane; k < 256; k += 64) edsum += ws[128 + k];
    for (int off = 1; off < 64; off <<= 1) {
        vsum  += __shfl_xor(vsum, off);
        csum  += __shfl_xor(csum, off);
        edsum += __shfl_xor(edsum, off);
    }
    if (lane == 0) {
        double vloss  = vsum / (3.0 * csum);
        double eloss  = ws[64] / (double)N_EX;
        double edloss = edsum / (double)N_EDGE;
        double total  = vloss + eloss + edloss;
        out[0] = (float)total;
        out[1] = (float)vloss;
        out[2] = (float)eloss;
        out[3] = (float)edloss;
    }
}

extern "C" void kernel_launch(void* const* d_in, const int* in_sizes, int n_in,
                              void* d_out, int out_size, void* d_ws, size_t ws_size,
                              hipStream_t stream) {
    const float* pv     = (const float*)d_in[0];
    const float* pe     = (const float*)d_in[1];
    const float* pedge  = (const float*)d_in[2];
    const float* tv     = (const float*)d_in[3];
    const int*   te     = (const int*)d_in[4];
    const float* elab   = (const float*)d_in[5];
    const int*   counts = (const int*)d_in[6];
    double* ws = (double*)d_ws;
    float* out = (float*)d_out;

    hipLaunchKernelGGL(hungarian_kernel, dim3(NB), dim3(64), 0, stream, pv, pe, tv, counts, ws);
    hipLaunchKernelGGL(bce_exist_kernel, dim3(1), dim3(256), 0, stream, pe, te, ws + 64);
    hipLaunchKernelGGL(bce_edge_kernel, dim3(256), dim3(256), 0, stream, pedge, elab, ws + 128);
    hipLaunchKernelGGL(finalize_kernel, dim3(1), dim3(64), 0, stream, ws, counts, out);
}